// Round 1
// baseline (280.628 us; speedup 1.0000x reference)
//
#include <hip/hip_runtime.h>

#define W 512
#define H 512
#define NSLICES 48          // 16 batch * 3 channels
#define TX 32
#define TY 32
#define HALO 5
#define KS 11
#define ITX (TX + 2*HALO)   // 42
#define ITY (TY + 2*HALO)   // 42
#define LSP 44              // padded LDS row stride (multiple of 4 for float4 align)
#define C1_SSIM 0.0001f     // 0.01^2
#define C2_SSIM 0.0009f     // 0.03^2
#define NTOTAL 12582912.0f  // 16*3*512*512

__device__ inline void fma4(float4& acc, float g, const float4& v) {
    acc.x = fmaf(g, v.x, acc.x);
    acc.y = fmaf(g, v.y, acc.y);
    acc.z = fmaf(g, v.z, acc.z);
    acc.w = fmaf(g, v.w, acc.w);
}

__device__ inline float ssim_px(float ux, float uy, float uxx, float uyy, float uxy) {
    const float uxuy = ux * uy;
    const float a = 2.f * uxuy + C1_SSIM;
    const float b = 2.f * (uxy - uxuy) + C2_SSIM;
    const float c = ux * ux + uy * uy + C1_SSIM;
    const float d = (uxx - ux * ux) + (uyy - uy * uy) + C2_SSIM;
    return (a * b) / (c * d);
}

__global__ __launch_bounds__(256)
void ssim_main(const float* __restrict__ simg, const float* __restrict__ timg,
               const float* __restrict__ k2d, float* __restrict__ accum) {
    __shared__ float ls[ITY][LSP];
    __shared__ float lt[ITY][LSP];
    __shared__ float hb[5][ITY][TX];
    __shared__ float gw[16];
    __shared__ float red[4];

    const int tid = threadIdx.x;
    const int bz = blockIdx.z;
    const float* sp = simg + (size_t)bz * (W * H);
    const float* tp = timg + (size_t)bz * (W * H);

    // Separable 1-D weights = row sums of the normalized 2-D kernel.
    if (tid < KS) {
        float acc = 0.f;
        #pragma unroll
        for (int j = 0; j < KS; ++j) acc += k2d[tid * KS + j];
        gw[tid] = acc;
    }

    // ---- Stage s,t tile (with halo) into LDS, zero-padded at image edges ----
    const int x0 = blockIdx.x * TX - HALO;
    const int y0 = blockIdx.y * TY - HALO;
    for (int i = tid; i < ITX * ITY; i += 256) {
        const int yy = i / ITX;
        const int xx = i - yy * ITX;
        const int gx = x0 + xx;
        const int gy = y0 + yy;
        float sv = 0.f, tv = 0.f;
        if (gx >= 0 && gx < W && gy >= 0 && gy < H) {
            const int idx = gy * W + gx;
            sv = sp[idx];
            tv = tp[idx];
        }
        ls[yy][xx] = sv;
        lt[yy][xx] = tv;
    }
    __syncthreads();

    // ---- Horizontal pass: 5 channels (s, t, s*s, t*t, s*t) convolved in x ----
    // 42 rows x 8 quads-of-4 = 336 work items.
    for (int q = tid; q < ITY * (TX / 4); q += 256) {
        const int yy = q >> 3;
        const int ox = (q & 7) * 4;
        const float4* p4s = (const float4*)&ls[yy][ox];
        const float4* p4t = (const float4*)&lt[yy][ox];
        const float4 s0 = p4s[0], s1 = p4s[1], s2 = p4s[2], s3 = p4s[3];
        const float4 t0 = p4t[0], t1 = p4t[1], t2 = p4t[2], t3 = p4t[3];
        const float vs[16] = {s0.x, s0.y, s0.z, s0.w, s1.x, s1.y, s1.z, s1.w,
                              s2.x, s2.y, s2.z, s2.w, s3.x, s3.y, s3.z, s3.w};
        const float vt[16] = {t0.x, t0.y, t0.z, t0.w, t1.x, t1.y, t1.z, t1.w,
                              t2.x, t2.y, t2.z, t2.w, t3.x, t3.y, t3.z, t3.w};
        float hs[4]  = {0, 0, 0, 0};
        float ht[4]  = {0, 0, 0, 0};
        float hss[4] = {0, 0, 0, 0};
        float htt[4] = {0, 0, 0, 0};
        float hst[4] = {0, 0, 0, 0};
        #pragma unroll
        for (int k = 0; k < KS; ++k) {
            const float gk = gw[k];
            #pragma unroll
            for (int m = 0; m < 4; ++m) {
                const float sv = vs[m + k];
                const float tv = vt[m + k];
                const float gs = gk * sv;
                const float gt = gk * tv;
                hs[m]  += gs;
                ht[m]  += gt;
                hss[m] = fmaf(gs, sv, hss[m]);
                htt[m] = fmaf(gt, tv, htt[m]);
                hst[m] = fmaf(gs, tv, hst[m]);
            }
        }
        *(float4*)&hb[0][yy][ox] = make_float4(hs[0],  hs[1],  hs[2],  hs[3]);
        *(float4*)&hb[1][yy][ox] = make_float4(ht[0],  ht[1],  ht[2],  ht[3]);
        *(float4*)&hb[2][yy][ox] = make_float4(hss[0], hss[1], hss[2], hss[3]);
        *(float4*)&hb[3][yy][ox] = make_float4(htt[0], htt[1], htt[2], htt[3]);
        *(float4*)&hb[4][yy][ox] = make_float4(hst[0], hst[1], hst[2], hst[3]);
    }
    __syncthreads();

    // ---- Vertical pass + SSIM: each thread owns 4 consecutive output px ----
    const int oy = tid >> 3;
    const int ox = (tid & 7) * 4;
    float4 ux  = {0, 0, 0, 0};
    float4 uy  = {0, 0, 0, 0};
    float4 uxx = {0, 0, 0, 0};
    float4 uyy = {0, 0, 0, 0};
    float4 uxy = {0, 0, 0, 0};
    #pragma unroll
    for (int k = 0; k < KS; ++k) {
        const float gk = gw[k];
        fma4(ux,  gk, *(const float4*)&hb[0][oy + k][ox]);
        fma4(uy,  gk, *(const float4*)&hb[1][oy + k][ox]);
        fma4(uxx, gk, *(const float4*)&hb[2][oy + k][ox]);
        fma4(uyy, gk, *(const float4*)&hb[3][oy + k][ox]);
        fma4(uxy, gk, *(const float4*)&hb[4][oy + k][ox]);
    }
    float sum = ssim_px(ux.x, uy.x, uxx.x, uyy.x, uxy.x)
              + ssim_px(ux.y, uy.y, uxx.y, uyy.y, uxy.y)
              + ssim_px(ux.z, uy.z, uxx.z, uyy.z, uxy.z)
              + ssim_px(ux.w, uy.w, uxx.w, uyy.w, uxy.w);

    // ---- Block reduction: wave shuffle, then cross-wave via LDS ----
    #pragma unroll
    for (int off = 32; off > 0; off >>= 1)
        sum += __shfl_down(sum, off, 64);
    if ((tid & 63) == 0) red[tid >> 6] = sum;
    __syncthreads();
    if (tid == 0) {
        atomicAdd(accum, red[0] + red[1] + red[2] + red[3]);
    }
}

__global__ void ssim_final(const float* __restrict__ accum, float* __restrict__ out) {
    out[0] = 1.f - accum[0] * (1.f / NTOTAL);
}

extern "C" void kernel_launch(void* const* d_in, const int* in_sizes, int n_in,
                              void* d_out, int out_size, void* d_ws, size_t ws_size,
                              hipStream_t stream) {
    const float* s   = (const float*)d_in[0];
    const float* t   = (const float*)d_in[1];
    const float* k2d = (const float*)d_in[2];
    float* out   = (float*)d_out;
    float* accum = (float*)d_ws;

    hipMemsetAsync(accum, 0, sizeof(float), stream);
    dim3 grid(W / TX, H / TY, NSLICES);
    ssim_main<<<grid, 256, 0, stream>>>(s, t, k2d, accum);
    ssim_final<<<1, 1, 0, stream>>>(accum, out);
}